// Round 5
// baseline (192.426 us; speedup 1.0000x reference)
//
#include <hip/hip_runtime.h>
#include <hip/hip_fp16.h>

// ---------------------------------------------------------------------------
// Pipeline (tier 1):
//   memset(counts) -> hist -> conv(gemb fp32->fp16) -> scan(3, slice bases
//   fused into scan_top) -> bin (edges -> per-slice contiguous buckets,
//   payload planar) -> passB (XCD-affine slice scatter into CSR pack)
//   -> gather (one wave/node, fp16 rows, 8-way unroll)
// Slices are dst>>14 (16384 nodes) so slice bucket regions are exact CSR
// sub-ranges: base[s] = offsets[s<<14].
// ---------------------------------------------------------------------------

#define SCAN_ELEMS   1024
#define SCAN_THREADS 256
#define NSLOT        8
#define SLICE_SHIFT  14
#define PB_BLOCKS    192   // passB blocks per slice slot

__global__ void hist_kernel(const int* __restrict__ dst, int* __restrict__ counts, int E) {
    int i = (blockIdx.x * blockDim.x + threadIdx.x) * 4;
    if (i + 3 < E) {
        int4 d = *(const int4*)(dst + i);
        atomicAdd(&counts[d.x], 1);
        atomicAdd(&counts[d.y], 1);
        atomicAdd(&counts[d.z], 1);
        atomicAdd(&counts[d.w], 1);
    } else {
        for (int k = i; k < E; ++k) atomicAdd(&counts[dst[k]], 1);
    }
}

__global__ void conv_half_kernel(const float* __restrict__ g, __half* __restrict__ h, int n) {
    int i = (blockIdx.x * blockDim.x + threadIdx.x) * 8;
    if (i + 7 < n) {
        float4 a = *(const float4*)(g + i);
        float4 b = *(const float4*)(g + i + 4);
        __half2 h0 = __floats2half2_rn(a.x, a.y);
        __half2 h1 = __floats2half2_rn(a.z, a.w);
        __half2 h2 = __floats2half2_rn(b.x, b.y);
        __half2 h3 = __floats2half2_rn(b.z, b.w);
        int4 o;
        o.x = *(int*)&h0; o.y = *(int*)&h1; o.z = *(int*)&h2; o.w = *(int*)&h3;
        *(int4*)(h + i) = o;
    } else {
        for (int k = i; k < n; ++k) h[k] = __float2half(g[k]);
    }
}

// Phase A: per-block sums of 1024 counts each.
__global__ void scan_block_sums(const int* __restrict__ counts,
                                int* __restrict__ bsums, int N) {
    __shared__ int red[SCAN_THREADS];
    int tid  = threadIdx.x;
    int base = blockIdx.x * SCAN_ELEMS + tid * 4;
    int s = 0;
    if (base + 3 < N) {
        int4 c = *(const int4*)(counts + base);
        s = c.x + c.y + c.z + c.w;
    } else {
        int lim = min(base + 4, N);
        for (int k = base; k < lim; ++k) s += counts[k];
    }
    red[tid] = s;
    __syncthreads();
    for (int off = SCAN_THREADS / 2; off > 0; off >>= 1) {
        if (tid < off) red[tid] += red[tid + off];
        __syncthreads();
    }
    if (tid == 0) bsums[blockIdx.x] = red[0];
}

// Phase B: scan the B block-sums (exclusive, in place); offsets[N] = total.
// Also emit slice bucket cursors: scursor[s] = offsets[s<<SLICE_SHIFT]
// (= exclusive prefix at scan block 16*s, since 16*1024 nodes per slice).
__global__ void scan_top(int* __restrict__ bsums, int* __restrict__ offsets_N,
                         int* __restrict__ scursor, int B) {
    __shared__ int sh[128];
    __shared__ int shv[128];
    int t = threadIdx.x;
    int v = (t < B) ? bsums[t] : 0;
    sh[t] = v;
    shv[t] = v;
    __syncthreads();
    for (int off = 1; off < 128; off <<= 1) {
        int u = (t >= off) ? sh[t - off] : 0;
        __syncthreads();
        sh[t] += u;
        __syncthreads();
    }
    if (t < B) bsums[t] = sh[t] - v;          // exclusive
    if (t == 127) offsets_N[0] = sh[127];     // total = E
    if (t < NSLOT) {
        int j = t * 16;                        // scan block at slice boundary
        scursor[t] = sh[j] - shv[j];           // exclusive prefix (== total for j>=B)
    }
}

// Phase C: local exclusive scan per block + block base -> offsets & cursor.
__global__ void scan_final(const int* __restrict__ counts,
                           const int* __restrict__ bsums,
                           int* __restrict__ offsets,
                           int* __restrict__ cursor, int N) {
    __shared__ int sh[SCAN_THREADS];
    int tid  = threadIdx.x;
    int base = blockIdx.x * SCAN_ELEMS + tid * 4;
    int4 c = make_int4(0, 0, 0, 0);
    if (base + 3 < N) {
        c = *(const int4*)(counts + base);
    } else {
        if (base + 0 < N) c.x = counts[base + 0];
        if (base + 1 < N) c.y = counts[base + 1];
        if (base + 2 < N) c.z = counts[base + 2];
    }
    int tsum = c.x + c.y + c.z + c.w;
    sh[tid] = tsum;
    __syncthreads();
    for (int off = 1; off < SCAN_THREADS; off <<= 1) {
        int u = (tid >= off) ? sh[tid - off] : 0;
        __syncthreads();
        sh[tid] += u;
        __syncthreads();
    }
    int excl = sh[tid] - tsum;
    int b0 = bsums[blockIdx.x] + excl;
    int4 o;
    o.x = b0;
    o.y = o.x + c.x;
    o.z = o.y + c.y;
    o.w = o.z + c.z;
    if (base + 3 < N) {
        *(int4*)(offsets + base) = o;
        *(int4*)(cursor  + base) = o;
    } else {
        if (base + 0 < N) { offsets[base + 0] = o.x; cursor[base + 0] = o.x; }
        if (base + 1 < N) { offsets[base + 1] = o.y; cursor[base + 1] = o.y; }
        if (base + 2 < N) { offsets[base + 2] = o.z; cursor[base + 2] = o.z; }
    }
}

// Bin pass: read each edge once; append payload to its slice's contiguous
// bucket via LDS-aggregated cursors. Writes are ~1KB contiguous runs.
__global__ void bin_kernel(const int* __restrict__ src,
                           const float* __restrict__ efeat,
                           const int* __restrict__ dst,
                           int* __restrict__ scursor,
                           int* __restrict__ bdst,
                           int2* __restrict__ bpay, int E) {
    __shared__ int lcount[NSLOT];
    __shared__ int lbase[NSLOT];
    int tid = threadIdx.x;
    if (tid < NSLOT) lcount[tid] = 0;
    __syncthreads();

    int e0 = (blockIdx.x * blockDim.x + tid) * 8;
    int dv[8], sv[8], sl[8], rk[8];
    float ev[8];

    if (e0 + 7 < E) {
        *(int4*)&dv[0] = *(const int4*)(dst + e0);
        *(int4*)&dv[4] = *(const int4*)(dst + e0 + 4);
        *(int4*)&sv[0] = *(const int4*)(src + e0);
        *(int4*)&sv[4] = *(const int4*)(src + e0 + 4);
        *(float4*)&ev[0] = *(const float4*)(efeat + e0);
        *(float4*)&ev[4] = *(const float4*)(efeat + e0 + 4);
#pragma unroll 8
        for (int k = 0; k < 8; ++k) {
            sl[k] = dv[k] >> SLICE_SHIFT;
            rk[k] = atomicAdd(&lcount[sl[k]], 1);
        }
    } else {
#pragma unroll 8
        for (int k = 0; k < 8; ++k) {
            if (e0 + k < E) {
                dv[k] = dst[e0 + k];
                sv[k] = src[e0 + k];
                ev[k] = efeat[e0 + k];
                sl[k] = dv[k] >> SLICE_SHIFT;
                rk[k] = atomicAdd(&lcount[sl[k]], 1);
            } else {
                sl[k] = -1;
            }
        }
    }
    __syncthreads();
    if (tid < NSLOT) lbase[tid] = atomicAdd(&scursor[tid], lcount[tid]);
    __syncthreads();
#pragma unroll 8
    for (int k = 0; k < 8; ++k) {
        if (sl[k] >= 0) {
            int pos = lbase[sl[k]] + rk[k];
            bdst[pos] = dv[k];
            bpay[pos] = make_int2(sv[k], __float_as_int(ev[k]));
        }
    }
}

// Pass B: slice slot = blockIdx&7 (XCD-affine). Stream the slice's bucket
// coalescedly; scatter payload into CSR pack with L2-local cursor atomics.
__global__ void passb_kernel(const int* __restrict__ bdst,
                             const int2* __restrict__ bpay,
                             const int* __restrict__ offsets,
                             int* __restrict__ cursor,
                             int2* __restrict__ pack, int N) {
    int slot  = blockIdx.x & (NSLOT - 1);
    int chunk = blockIdx.x >> 3;
    int lo = offsets[min(slot << SLICE_SHIFT, N)];
    int hi = offsets[min((slot + 1) << SLICE_SHIFT, N)];
    int idx  = chunk * blockDim.x + threadIdx.x;
    int step = (gridDim.x >> 3) * blockDim.x;
    for (int k = lo + idx; k < hi; k += step) {
        int d   = bdst[k];
        int2 py = bpay[k];
        int p = atomicAdd(&cursor[d], 1);
        pack[p] = py;
    }
}

// Gather: one wave per node, lane = feature, fp16 rows, 8-way unroll.
__global__ void gather_h_kernel(const __half* __restrict__ hg,
                                const int2* __restrict__ pack,
                                const int* __restrict__ offsets,
                                float* __restrict__ out, int N) {
    int wid  = (blockIdx.x * blockDim.x + threadIdx.x) >> 6;
    int lane = threadIdx.x & 63;
    if (wid >= N) return;

    int beg = offsets[wid];
    int end = offsets[wid + 1];

    float a0 = 0.f, a1 = 0.f, a2 = 0.f, a3 = 0.f;
    float a4 = 0.f, a5 = 0.f, a6 = 0.f, a7 = 0.f;
    float ea = 0.f, eb = 0.f;
    int j = beg;
    for (; j + 7 < end; j += 8) {
        int2 v0 = pack[j];     int2 v1 = pack[j + 1];
        int2 v2 = pack[j + 2]; int2 v3 = pack[j + 3];
        int2 v4 = pack[j + 4]; int2 v5 = pack[j + 5];
        int2 v6 = pack[j + 6]; int2 v7 = pack[j + 7];
        a0 += __half2float(hg[(size_t)v0.x * 64 + lane]);
        a1 += __half2float(hg[(size_t)v1.x * 64 + lane]);
        a2 += __half2float(hg[(size_t)v2.x * 64 + lane]);
        a3 += __half2float(hg[(size_t)v3.x * 64 + lane]);
        a4 += __half2float(hg[(size_t)v4.x * 64 + lane]);
        a5 += __half2float(hg[(size_t)v5.x * 64 + lane]);
        a6 += __half2float(hg[(size_t)v6.x * 64 + lane]);
        a7 += __half2float(hg[(size_t)v7.x * 64 + lane]);
        ea += __int_as_float(v0.y) + __int_as_float(v1.y) +
              __int_as_float(v2.y) + __int_as_float(v3.y);
        eb += __int_as_float(v4.y) + __int_as_float(v5.y) +
              __int_as_float(v6.y) + __int_as_float(v7.y);
    }
    for (; j + 3 < end; j += 4) {
        int2 v0 = pack[j];     int2 v1 = pack[j + 1];
        int2 v2 = pack[j + 2]; int2 v3 = pack[j + 3];
        a0 += __half2float(hg[(size_t)v0.x * 64 + lane]);
        a1 += __half2float(hg[(size_t)v1.x * 64 + lane]);
        a2 += __half2float(hg[(size_t)v2.x * 64 + lane]);
        a3 += __half2float(hg[(size_t)v3.x * 64 + lane]);
        ea += __int_as_float(v0.y) + __int_as_float(v1.y) +
              __int_as_float(v2.y) + __int_as_float(v3.y);
    }
    for (; j < end; ++j) {
        int2 v = pack[j];
        a0 += __half2float(hg[(size_t)v.x * 64 + lane]);
        ea += __int_as_float(v.y);
    }
    out[(size_t)wid * 65 + lane] = ((a0 + a1) + (a2 + a3)) + ((a4 + a5) + (a6 + a7));
    if (lane == 0) out[(size_t)wid * 65 + 64] = ea + eb;
}

// ------------------------- tier-2 fallback kernels -------------------------

__global__ void scatter_sliced(const int* __restrict__ src,
                               const float* __restrict__ efeat,
                               const int* __restrict__ dst,
                               int* __restrict__ cursor,
                               int2* __restrict__ pack,
                               int E, int slice_n) {
    int s = blockIdx.x & (NSLOT - 1);
    int c = blockIdx.x >> 3;
    int i = (c * 256 + threadIdx.x) * 4;
    int lo = s * slice_n;
    int hi = lo + slice_n;

    if (i + 3 < E) {
        int4 d = *(const int4*)(dst + i);
        if (d.x >= lo && d.x < hi) {
            int p = atomicAdd(&cursor[d.x], 1);
            pack[p] = make_int2(src[i + 0], __float_as_int(efeat[i + 0]));
        }
        if (d.y >= lo && d.y < hi) {
            int p = atomicAdd(&cursor[d.y], 1);
            pack[p] = make_int2(src[i + 1], __float_as_int(efeat[i + 1]));
        }
        if (d.z >= lo && d.z < hi) {
            int p = atomicAdd(&cursor[d.z], 1);
            pack[p] = make_int2(src[i + 2], __float_as_int(efeat[i + 2]));
        }
        if (d.w >= lo && d.w < hi) {
            int p = atomicAdd(&cursor[d.w], 1);
            pack[p] = make_int2(src[i + 3], __float_as_int(efeat[i + 3]));
        }
    } else {
        for (int k = i; k < E; ++k) {
            int d = dst[k];
            if (d >= lo && d < hi) {
                int p = atomicAdd(&cursor[d], 1);
                pack[p] = make_int2(src[k], __float_as_int(efeat[k]));
            }
        }
    }
}

__global__ void gather_f_kernel(const float* __restrict__ gemb,
                                const int2* __restrict__ pack,
                                const int* __restrict__ offsets,
                                float* __restrict__ out, int N) {
    int wid  = (blockIdx.x * blockDim.x + threadIdx.x) >> 6;
    int lane = threadIdx.x & 63;
    if (wid >= N) return;
    int beg = offsets[wid];
    int end = offsets[wid + 1];
    float a0 = 0.f, a1 = 0.f, a2 = 0.f, a3 = 0.f, ea = 0.f;
    int j = beg;
    for (; j + 3 < end; j += 4) {
        int2 v0 = pack[j];     int2 v1 = pack[j + 1];
        int2 v2 = pack[j + 2]; int2 v3 = pack[j + 3];
        a0 += gemb[(size_t)v0.x * 64 + lane];
        a1 += gemb[(size_t)v1.x * 64 + lane];
        a2 += gemb[(size_t)v2.x * 64 + lane];
        a3 += gemb[(size_t)v3.x * 64 + lane];
        ea += __int_as_float(v0.y) + __int_as_float(v1.y) +
              __int_as_float(v2.y) + __int_as_float(v3.y);
    }
    for (; j < end; ++j) {
        int2 v = pack[j];
        a0 += gemb[(size_t)v.x * 64 + lane];
        ea += __int_as_float(v.y);
    }
    out[(size_t)wid * 65 + lane] = (a0 + a1) + (a2 + a3);
    if (lane == 0) out[(size_t)wid * 65 + 64] = ea;
}

__global__ void atomic_fallback_kernel(const float* __restrict__ gemb,
                                       const float* __restrict__ efeat,
                                       const int* __restrict__ src,
                                       const int* __restrict__ dst,
                                       float* __restrict__ out, int E) {
    int eidx = blockIdx.x * 4 + (threadIdx.x >> 6);
    int lane = threadIdx.x & 63;
    if (eidx >= E) return;
    int s = src[eidx];
    int d = dst[eidx];
    float v = gemb[(size_t)s * 64 + lane];
    atomicAdd(&out[(size_t)d * 65 + lane], v);
    if (lane == 0) atomicAdd(&out[(size_t)d * 65 + 64], efeat[eidx]);
}

// ---------------------------------------------------------------------------

extern "C" void kernel_launch(void* const* d_in, const int* in_sizes, int n_in,
                              void* d_out, int out_size, void* d_ws, size_t ws_size,
                              hipStream_t stream) {
    const float* gemb  = (const float*)d_in[0];   // [N, 64]
    const float* efeat = (const float*)d_in[1];   // [E]
    const int*   src   = (const int*)d_in[2];     // [E]
    const int*   dst   = (const int*)d_in[3];     // [E]
    float*       out   = (float*)d_out;           // [N, 65]

    const int N = in_sizes[0] / 64;
    const int E = in_sizes[1];
    const int B = (N + SCAN_ELEMS - 1) / SCAN_ELEMS;   // scan blocks (<=128)

    auto aln = [](size_t x) { return (x + 15) & ~(size_t)15; };

    size_t off_counts  = 0;
    size_t off_offsets = off_counts  + aln((size_t)N * 4);
    size_t off_cursor  = off_offsets + aln((size_t)(N + 1) * 4);
    size_t off_bsums   = off_cursor  + aln((size_t)N * 4);
    size_t off_scursor = off_bsums   + aln(128 * 4);
    size_t off_pack    = off_scursor + aln(NSLOT * 4);
    size_t needed_t2   = off_pack    + (size_t)E * 8;
    size_t off_bdst    = aln(needed_t2);
    size_t off_bpay    = off_bdst    + aln((size_t)E * 4);
    size_t off_hgemb   = off_bpay    + aln((size_t)E * 8);
    size_t needed_t1   = off_hgemb   + (size_t)N * 64 * 2;

    char* ws = (char*)d_ws;
    int*  counts  = (int*)(ws + off_counts);
    int*  offsets = (int*)(ws + off_offsets);
    int*  cursor  = (int*)(ws + off_cursor);
    int*  bsums   = (int*)(ws + off_bsums);
    int*  scursor = (int*)(ws + off_scursor);
    int2* pack    = (int2*)(ws + off_pack);

    if (ws_size < needed_t2 || B > 128) {
        // tier 3: atomic fallback
        hipMemsetAsync(d_out, 0, (size_t)out_size * sizeof(float), stream);
        int blocks = (E + 3) / 4;
        atomic_fallback_kernel<<<blocks, 256, 0, stream>>>(gemb, efeat, src, dst, out, E);
        return;
    }

    hipMemsetAsync(counts, 0, (size_t)N * 4, stream);

    int h_threads = (E + 3) / 4;
    int h_blocks  = (h_threads + 255) / 256;
    hist_kernel<<<h_blocks, 256, 0, stream>>>(dst, counts, E);

    if (ws_size >= needed_t1) {
        // tier 1: full pipeline
        int*    bdst  = (int*)(ws + off_bdst);
        int2*   bpay  = (int2*)(ws + off_bpay);
        __half* hgemb = (__half*)(ws + off_hgemb);

        int n_emb = N * 64;
        int c_blocks = (n_emb / 8 + 255) / 256;
        conv_half_kernel<<<c_blocks, 256, 0, stream>>>(gemb, hgemb, n_emb);

        scan_block_sums<<<B, SCAN_THREADS, 0, stream>>>(counts, bsums, N);
        scan_top<<<1, 128, 0, stream>>>(bsums, offsets + N, scursor, B);
        scan_final<<<B, SCAN_THREADS, 0, stream>>>(counts, bsums, offsets, cursor, N);

        int b_threads = (E + 7) / 8;
        int b_blocks  = (b_threads + 255) / 256;
        bin_kernel<<<b_blocks, 256, 0, stream>>>(src, efeat, dst, scursor, bdst, bpay, E);

        passb_kernel<<<PB_BLOCKS * NSLOT, 256, 0, stream>>>(bdst, bpay, offsets, cursor, pack, N);

        int g_blocks = (N + 3) / 4;
        gather_h_kernel<<<g_blocks, 256, 0, stream>>>(hgemb, pack, offsets, out, N);
    } else {
        // tier 2: round-4 pipeline
        scan_block_sums<<<B, SCAN_THREADS, 0, stream>>>(counts, bsums, N);
        scan_top<<<1, 128, 0, stream>>>(bsums, offsets + N, scursor, B);
        scan_final<<<B, SCAN_THREADS, 0, stream>>>(counts, bsums, offsets, cursor, N);

        int slice_n = (N + NSLOT - 1) / NSLOT;
        scatter_sliced<<<h_blocks * NSLOT, 256, 0, stream>>>(src, efeat, dst, cursor, pack, E, slice_n);

        int g_blocks = (N + 3) / 4;
        gather_f_kernel<<<g_blocks, 256, 0, stream>>>(gemb, pack, offsets, out, N);
    }
}